// Round 1
// baseline (424.599 us; speedup 1.0000x reference)
//
#include <hip/hip_runtime.h>
#include <math.h>

#define Hdim 1024
#define Vdim 50257
#define Ldim 512

#define LOGITS_BLOCKS 2048   // k_logits_lse grid; 4 waves/block -> 8192 waves

// ---------- reduction helpers (wave = 64) ----------
__device__ __forceinline__ float waveReduceSum(float v) {
    #pragma unroll
    for (int off = 32; off > 0; off >>= 1) v += __shfl_down(v, off, 64);
    return v;
}
__device__ __forceinline__ float waveReduceMax(float v) {
    #pragma unroll
    for (int off = 32; off > 0; off >>= 1) v = fmaxf(v, __shfl_down(v, off, 64));
    return v;
}
template<int NW>
__device__ __forceinline__ float blockReduceSum(float v, float* red) {
    v = waveReduceSum(v);
    const int lane = threadIdx.x & 63, wid = threadIdx.x >> 6;
    if (lane == 0) red[wid] = v;
    __syncthreads();
    float s = red[0];
    #pragma unroll
    for (int i = 1; i < NW; i++) s += red[i];
    __syncthreads();
    return s;
}

// ---------- K1: att[l] = Ww[l,:]·[emb[x];hidden] + bw[l]  (blocks 0..511)
//             gh[r]  = Whh[r,:]·hidden + bhh[r]            (blocks 512..3583)
//             blocks 512..515 also zero the wctx accumulator
__global__ __launch_bounds__(256) void k_att_gh(
    const int* __restrict__ xp, const float* __restrict__ hidden,
    const float* __restrict__ emb, const float* __restrict__ Ww,
    const float* __restrict__ bw, const float* __restrict__ Whh,
    const float* __restrict__ bhh, float* __restrict__ att,
    float* __restrict__ gh, float* __restrict__ wctx)
{
    __shared__ float red[4];
    const int t = threadIdx.x, bid = blockIdx.x;
    float acc = 0.f;
    if (bid < Ldim) {
        const int tok = xp[0];
        const float4* wrow = (const float4*)(Ww + (size_t)bid * (2 * Hdim));
        const float4* ev   = (const float4*)(emb + (size_t)tok * Hdim);
        const float4* hv   = (const float4*)hidden;
        #pragma unroll
        for (int k = 0; k < 2; ++k) {
            const int j = t * 2 + k;                       // 0..511 float4s
            const float4 w = wrow[j];
            const float4 c = (j < Hdim / 4) ? ev[j] : hv[j - Hdim / 4];
            acc += w.x * c.x + w.y * c.y + w.z * c.z + w.w * c.w;
        }
        acc = blockReduceSum<4>(acc, red);
        if (t == 0) att[bid] = acc + bw[bid];
    } else {
        const int r = bid - Ldim;
        if (r < 4) wctx[r * 256 + t] = 0.f;                // init accumulator
        const float4* wrow = (const float4*)(Whh + (size_t)r * Hdim);
        const float4 w = wrow[t];
        const float4 h = ((const float4*)hidden)[t];
        acc = w.x * h.x + w.y * h.y + w.z * h.z + w.w * h.w;
        acc = blockReduceSum<4>(acc, red);
        if (t == 0) gh[r] = acc + bhh[r];
    }
}

// ---------- K2: softmax(att) recomputed per block (2 KB from L2), then
//                wctx[i] += sum over 8 rows of w[l]*enc[l,i] (64 blocks) ----
__global__ __launch_bounds__(256) void k_soft_wctx(
    const float* __restrict__ att, const float* __restrict__ enc,
    float* __restrict__ out_w, float* __restrict__ wctx)
{
    __shared__ float red[4];
    __shared__ float wsm[512];
    __shared__ float bm, bs;
    const int t = threadIdx.x, b = blockIdx.x;
    const int lane = t & 63, wid = t >> 6;

    const float v0 = att[t], v1 = att[t + 256];
    float m = waveReduceMax(fmaxf(v0, v1));
    if (lane == 0) red[wid] = m;
    __syncthreads();
    if (t == 0) bm = fmaxf(fmaxf(red[0], red[1]), fmaxf(red[2], red[3]));
    __syncthreads();
    const float e0 = __expf(v0 - bm), e1 = __expf(v1 - bm);
    float s = waveReduceSum(e0 + e1);
    if (lane == 0) red[wid] = s;
    __syncthreads();
    if (t == 0) bs = red[0] + red[1] + red[2] + red[3];
    __syncthreads();
    const float inv = 1.f / bs;
    const float w0 = e0 * inv, w1 = e1 * inv;
    wsm[t] = w0; wsm[t + 256] = w1;
    if (b == 0) { out_w[t] = w0; out_w[t + 256] = w1; }    // output 3
    __syncthreads();

    float4 acc = make_float4(0.f, 0.f, 0.f, 0.f);
    #pragma unroll
    for (int i = 0; i < 8; ++i) {
        const int l = b * 8 + i;
        const float w = wsm[l];
        const float4 e = ((const float4*)(enc + (size_t)l * Hdim))[t];
        acc.x += w * e.x; acc.y += w * e.y; acc.z += w * e.z; acc.w += w * e.w;
    }
    atomicAdd(&wctx[t * 4 + 0], acc.x);
    atomicAdd(&wctx[t * 4 + 1], acc.y);
    atomicAdd(&wctx[t * 4 + 2], acc.z);
    atomicAdd(&wctx[t * 4 + 3], acc.w);
}

// ---------- K3: c[r] = relu(Wc[r,:]·[emb[x];wctx] + bc[r]) (1024 blocks) ---
__global__ __launch_bounds__(256) void k_wc(
    const int* __restrict__ xp, const float* __restrict__ emb,
    const float* __restrict__ wctx, const float* __restrict__ Wc,
    const float* __restrict__ bc, float* __restrict__ cvec)
{
    __shared__ float red[4];
    const int t = threadIdx.x, r = blockIdx.x;
    const int tok = xp[0];
    const float4* wrow = (const float4*)(Wc + (size_t)r * (2 * Hdim));
    const float4* ev   = (const float4*)(emb + (size_t)tok * Hdim);
    const float4* cv   = (const float4*)wctx;
    float acc = 0.f;
    #pragma unroll
    for (int k = 0; k < 2; ++k) {
        const int j = t * 2 + k;
        const float4 w = wrow[j];
        const float4 c = (j < Hdim / 4) ? ev[j] : cv[j - Hdim / 4];
        acc += w.x * c.x + w.y * c.y + w.z * c.z + w.w * c.w;
    }
    acc = blockReduceSum<4>(acc, red);
    if (t == 0) cvec[r] = fmaxf(acc + bc[r], 0.f);
}

// ---------- K4: gi rows j, j+H, j+2H + GRU gate combine → h_new[j] ---------
__global__ __launch_bounds__(256) void k_gru(
    const float* __restrict__ Wih, const float* __restrict__ bih,
    const float* __restrict__ gh, const float* __restrict__ cvec,
    const float* __restrict__ hidden, float* __restrict__ hnew,
    float* __restrict__ out_h)
{
    __shared__ float red[4];
    const int t = threadIdx.x, j = blockIdx.x;              // 1024 blocks
    const float4 c = ((const float4*)cvec)[t];
    const float4 a = ((const float4*)(Wih + (size_t)j * Hdim))[t];
    const float4 b = ((const float4*)(Wih + (size_t)(j + Hdim) * Hdim))[t];
    const float4 d = ((const float4*)(Wih + (size_t)(j + 2 * Hdim) * Hdim))[t];
    float s0 = a.x * c.x + a.y * c.y + a.z * c.z + a.w * c.w;
    float s1 = b.x * c.x + b.y * c.y + b.z * c.z + b.w * c.w;
    float s2 = d.x * c.x + d.y * c.y + d.z * c.z + d.w * c.w;
    s0 = blockReduceSum<4>(s0, red);
    s1 = blockReduceSum<4>(s1, red);
    s2 = blockReduceSum<4>(s2, red);
    if (t == 0) {
        const float gir = s0 + bih[j];
        const float giz = s1 + bih[j + Hdim];
        const float gin = s2 + bih[j + 2 * Hdim];
        const float rr = 1.f / (1.f + __expf(-(gir + gh[j])));
        const float zz = 1.f / (1.f + __expf(-(giz + gh[j + Hdim])));
        const float nn = tanhf(gin + rr * gh[j + 2 * Hdim]);
        const float h = (1.f - zz) * nn + zz * hidden[j];
        hnew[j]  = h;
        out_h[j] = h;                                       // output 2
    }
}

// ---------- K5: wave-per-row logits + fused online-LSE partials ------------
// grid = LOGITS_BLOCKS blocks x 4 waves; wave handles rows r = bid*4+wid,
// stride 4*LOGITS_BLOCKS. Butterfly reduce -> all lanes hold the dot; each
// wave maintains an online (m,s); block combines 4 waves -> 1 partial.
__global__ __launch_bounds__(256) void k_logits_lse(
    const float* __restrict__ Wo, const float* __restrict__ bo,
    const float* __restrict__ h, float* __restrict__ logits,
    float* __restrict__ pm, float* __restrict__ ps)
{
    __shared__ float redm[4], reds[4];
    const int t = threadIdx.x, lane = t & 63, wid = t >> 6;
    const float4* h4 = (const float4*)h;
    const float4 hv0 = h4[lane], hv1 = h4[lane + 64],
                 hv2 = h4[lane + 128], hv3 = h4[lane + 192];
    float m = -1e30f, s = 0.f;
    for (int r = blockIdx.x * 4 + wid; r < Vdim; r += LOGITS_BLOCKS * 4) {
        const float4* w4 = (const float4*)(Wo + (size_t)r * Hdim);
        const float4 a0 = w4[lane], a1 = w4[lane + 64],
                     a2 = w4[lane + 128], a3 = w4[lane + 192];
        float acc = a0.x*hv0.x + a0.y*hv0.y + a0.z*hv0.z + a0.w*hv0.w
                  + a1.x*hv1.x + a1.y*hv1.y + a1.z*hv1.z + a1.w*hv1.w
                  + a2.x*hv2.x + a2.y*hv2.y + a2.z*hv2.z + a2.w*hv2.w
                  + a3.x*hv3.x + a3.y*hv3.y + a3.z*hv3.z + a3.w*hv3.w;
        #pragma unroll
        for (int off = 32; off > 0; off >>= 1) acc += __shfl_xor(acc, off, 64);
        const float lg = acc + bo[r];
        if (lane == 0) logits[r] = lg;
        const float nm = fmaxf(m, lg);                      // online LSE
        s = s * __expf(m - nm) + __expf(lg - nm);
        m = nm;
    }
    if (lane == 0) { redm[wid] = m; reds[wid] = s; }
    __syncthreads();
    if (t == 0) {
        float M = redm[0], S = reds[0];
        #pragma unroll
        for (int i = 1; i < 4; i++) {
            const float nm = fmaxf(M, redm[i]);
            S = S * __expf(M - nm) + reds[i] * __expf(redm[i] - nm);
            M = nm;
        }
        pm[blockIdx.x] = M; ps[blockIdx.x] = S;
    }
}

// ---------- K6: per-block redundant merge of partials -> logZ, then
//                in-place log_softmax: out[i] -= logZ (64 blocks) -----------
__global__ __launch_bounds__(256) void k_lse_out(
    const float* __restrict__ pm, const float* __restrict__ ps,
    float* __restrict__ out)
{
    __shared__ float redm[4], reds[4];
    __shared__ float slz;
    const int t = threadIdx.x, lane = t & 63, wid = t >> 6;
    float m = -1e30f, s = 0.f;
    #pragma unroll
    for (int i = t; i < LOGITS_BLOCKS; i += 256) {
        const float om = pm[i], os = ps[i];
        const float nm = fmaxf(m, om);
        s = s * __expf(m - nm) + os * __expf(om - nm);
        m = nm;
    }
    #pragma unroll
    for (int off = 32; off > 0; off >>= 1) {
        const float om = __shfl_xor(m, off, 64);
        const float os = __shfl_xor(s, off, 64);
        const float nm = fmaxf(m, om);
        s = s * __expf(m - nm) + os * __expf(om - nm);
        m = nm;
    }
    if (lane == 0) { redm[wid] = m; reds[wid] = s; }
    __syncthreads();
    if (t == 0) {
        float M = redm[0], S = reds[0];
        #pragma unroll
        for (int i = 1; i < 4; i++) {
            const float nm = fmaxf(M, redm[i]);
            S = S * __expf(M - nm) + reds[i] * __expf(redm[i] - nm);
            M = nm;
        }
        slz = M + logf(S);
    }
    __syncthreads();
    const float lz = slz;
    for (int i = blockIdx.x * 256 + t; i < Vdim; i += gridDim.x * 256)
        out[i] -= lz;
}

extern "C" void kernel_launch(void* const* d_in, const int* in_sizes, int n_in,
                              void* d_out, int out_size, void* d_ws, size_t ws_size,
                              hipStream_t stream)
{
    const int*   x      = (const int*)  d_in[0];
    const float* hidden = (const float*)d_in[1];   // [1,1,H]
    const float* enc    = (const float*)d_in[2];   // [L,H]
    const float* emb    = (const float*)d_in[3];   // [V,H]
    const float* Ww     = (const float*)d_in[4];   // [L,2H]
    const float* bw     = (const float*)d_in[5];   // [L]
    const float* Wc     = (const float*)d_in[6];   // [H,2H]
    const float* bc     = (const float*)d_in[7];   // [H]
    const float* Wih    = (const float*)d_in[8];   // [3H,H]
    const float* Whh    = (const float*)d_in[9];   // [3H,H]
    const float* bih    = (const float*)d_in[10];  // [3H]
    const float* bhh    = (const float*)d_in[11];  // [3H]
    const float* Wo     = (const float*)d_in[12];  // [V,H]
    const float* bo     = (const float*)d_in[13];  // [V]

    float* out      = (float*)d_out;
    float* out_logp = out;                 // [V]  output 1 (logits → in-place log_softmax)
    float* out_h    = out + Vdim;          // [H]  output 2
    float* out_w    = out + Vdim + Hdim;   // [L]  output 3

    float* ws   = (float*)d_ws;
    float* att  = ws;                      // 512
    float* wctx = ws + 512;                // 1024 (atomic accumulator, zeroed in K1)
    float* cvec = ws + 1536;               // 1024
    float* gh   = ws + 2560;               // 3072
    float* hnew = ws + 5632;               // 1024
    float* pm   = ws + 6656;               // LOGITS_BLOCKS
    float* psum = ws + 6656 + LOGITS_BLOCKS; // LOGITS_BLOCKS

    k_att_gh    <<<dim3(Ldim + 3 * Hdim), dim3(256), 0, stream>>>(x, hidden, emb, Ww, bw, Whh, bhh, att, gh, wctx);
    k_soft_wctx <<<dim3(64),              dim3(256), 0, stream>>>(att, enc, out_w, wctx);
    k_wc        <<<dim3(Hdim),            dim3(256), 0, stream>>>(x, emb, wctx, Wc, bc, cvec);
    k_gru       <<<dim3(Hdim),            dim3(256), 0, stream>>>(Wih, bih, gh, cvec, hidden, hnew, out_h);
    k_logits_lse<<<dim3(LOGITS_BLOCKS),   dim3(256), 0, stream>>>(Wo, bo, hnew, out_logp, pm, psum);
    k_lse_out   <<<dim3(64),              dim3(256), 0, stream>>>(pm, psum, out_logp);
}